// Round 1
// baseline (1936.498 us; speedup 1.0000x reference)
//
#include <hip/hip_runtime.h>
#include <hip/hip_bf16.h>

// Problem constants
#define E_DIM 1024
#define T_DIM 2048
#define B_DIM 2
#define H_DIM 16
#define HD_DIM 64
#define R_DIM 8
#define M_ROWS (T_DIM * B_DIM)   // 4096 rows for all projections

// ---------------------------------------------------------------------------
// Pass 1: Vu = dir + B@A  (store unscaled), per-block partial sums of Vu^2
// grid: (256, 2)  block: 256
// ---------------------------------------------------------------------------
__global__ __launch_bounds__(256) void dora_pass1(
    const float* __restrict__ dir_q, const float* __restrict__ A_q, const float* __restrict__ B_q,
    const float* __restrict__ dir_v, const float* __restrict__ A_v, const float* __restrict__ B_v,
    float* __restrict__ Wq, float* __restrict__ Wv, float* __restrict__ partials) {
  const int mat = blockIdx.y;
  const float* __restrict__ dir = mat ? dir_v : dir_q;
  const float* __restrict__ Am  = mat ? A_v   : A_q;
  const float* __restrict__ Bm  = mat ? B_v   : B_q;
  float* __restrict__ W = mat ? Wv : Wq;

  float sum = 0.0f;
  for (int idx = blockIdx.x * 256 + threadIdx.x; idx < E_DIM * E_DIM; idx += 256 * 256) {
    int i = idx >> 10;            // row
    int j = idx & (E_DIM - 1);    // col
    float v = dir[idx];
#pragma unroll
    for (int r = 0; r < R_DIM; ++r)
      v += Bm[i * R_DIM + r] * Am[r * E_DIM + j];
    W[idx] = v;
    sum += v * v;
  }
  // deterministic block reduction: wave shuffle then LDS
#pragma unroll
  for (int off = 32; off > 0; off >>= 1) sum += __shfl_down(sum, off);
  __shared__ float red[4];
  if ((threadIdx.x & 63) == 0) red[threadIdx.x >> 6] = sum;
  __syncthreads();
  if (threadIdx.x == 0)
    partials[mat * 256 + blockIdx.x] = (red[0] + red[1]) + (red[2] + red[3]);
}

// ---------------------------------------------------------------------------
// Pass 2: reduce 256 partials per matrix, compute scale = m / (||Vu||_F + 1e-8)
// grid: 1   block: 256
// ---------------------------------------------------------------------------
__global__ __launch_bounds__(256) void dora_pass2(
    const float* __restrict__ partials, const float* __restrict__ mag_q,
    const float* __restrict__ mag_v, float* __restrict__ scales) {
  __shared__ float red[4];
  for (int mat = 0; mat < 2; ++mat) {
    float s = partials[mat * 256 + threadIdx.x];
#pragma unroll
    for (int off = 32; off > 0; off >>= 1) s += __shfl_down(s, off);
    if ((threadIdx.x & 63) == 0) red[threadIdx.x >> 6] = s;
    __syncthreads();
    if (threadIdx.x == 0) {
      float tot = (red[0] + red[1]) + (red[2] + red[3]);
      float m = mat ? mag_v[0] : mag_q[0];
      scales[mat] = m / (sqrtf(tot) + 1e-8f);
    }
    __syncthreads();   // protect `red` reuse in next iteration
  }
}

// ---------------------------------------------------------------------------
// GEMM (NT): C[4096,1024] = scale * (A[4096,1024] @ W[1024,1024]^T) + bias
// 64x64 tile, BK=32, 256 threads, 4x4 microtile.
// LDS layout transposed: As[k][m] (stride 68 -> 16B aligned rows, b128 reads)
// grid: (64, 16)  block: 256
// ---------------------------------------------------------------------------
__global__ __launch_bounds__(256) void gemm_nt(
    const float* __restrict__ A, const float* __restrict__ W,
    const float* __restrict__ bias, const float* __restrict__ scale_ptr,
    float* __restrict__ C) {
  __shared__ __align__(16) float As[32][68];
  __shared__ __align__(16) float Bs[32][68];
  const int bm = blockIdx.x * 64;
  const int bn = blockIdx.y * 64;
  const int tid = threadIdx.x;
  const int tx = tid & 15;        // output col group
  const int ty = tid >> 4;        // output row group
  float acc[4][4] = {{0.0f}};

  for (int k0 = 0; k0 < E_DIM; k0 += 32) {
    // stage: 64 rows x 32 cols each of A-tile and W-tile, float4 loads,
    // transposed scalar LDS stores (4-way write conflict, acceptable)
#pragma unroll
    for (int i = 0; i < 2; ++i) {
      int idx = i * 256 + tid;          // 0..511 float4 units
      int r = idx >> 3;                 // 0..63
      int c4 = (idx & 7) << 2;          // 0,4,...,28
      float4 a = *reinterpret_cast<const float4*>(&A[(size_t)(bm + r) * E_DIM + k0 + c4]);
      As[c4 + 0][r] = a.x; As[c4 + 1][r] = a.y; As[c4 + 2][r] = a.z; As[c4 + 3][r] = a.w;
      float4 w = *reinterpret_cast<const float4*>(&W[(size_t)(bn + r) * E_DIM + k0 + c4]);
      Bs[c4 + 0][r] = w.x; Bs[c4 + 1][r] = w.y; Bs[c4 + 2][r] = w.z; Bs[c4 + 3][r] = w.w;
    }
    __syncthreads();
#pragma unroll
    for (int kk = 0; kk < 32; ++kk) {
      float4 av = *reinterpret_cast<const float4*>(&As[kk][ty << 2]);
      float4 bv = *reinterpret_cast<const float4*>(&Bs[kk][tx << 2]);
      float a[4] = {av.x, av.y, av.z, av.w};
      float b[4] = {bv.x, bv.y, bv.z, bv.w};
#pragma unroll
      for (int i = 0; i < 4; ++i)
#pragma unroll
        for (int j = 0; j < 4; ++j)
          acc[i][j] += a[i] * b[j];
    }
    __syncthreads();
  }

  const float scale = scale_ptr ? scale_ptr[0] : 1.0f;
  float4 bias4 = *reinterpret_cast<const float4*>(&bias[bn + (tx << 2)]);
  float bb[4] = {bias4.x, bias4.y, bias4.z, bias4.w};
#pragma unroll
  for (int i = 0; i < 4; ++i) {
    float4 o;
    o.x = scale * acc[i][0] + bb[0];
    o.y = scale * acc[i][1] + bb[1];
    o.z = scale * acc[i][2] + bb[2];
    o.w = scale * acc[i][3] + bb[3];
    *reinterpret_cast<float4*>(&C[(size_t)(bm + (ty << 2) + i) * E_DIM + bn + (tx << 2)]) = o;
  }
}

// ---------------------------------------------------------------------------
// Flash attention, fp32, one thread per query row.
// q[64] and O[64] live in registers; K/V tiles (64x64) staged in LDS;
// inner reads are block-uniform -> LDS broadcast. Per-key online softmax.
// grid: (T/128, B*H)  block: 128
// ---------------------------------------------------------------------------
__global__ __launch_bounds__(128) void attn_fp32(
    const float* __restrict__ qb, const float* __restrict__ kb,
    const float* __restrict__ vb, float* __restrict__ ob) {
  const int n = blockIdx.y;           // head index n = b*H + h
  const int b = n >> 4;
  const int h = n & 15;
  const int tq = blockIdx.x * 128 + threadIdx.x;   // query index
  const int col0 = h * HD_DIM;        // column offset inside E

  // load q row into registers
  float q[HD_DIM];
  const float* qrow = qb + ((size_t)tq * B_DIM + b) * E_DIM + col0;
#pragma unroll
  for (int d0 = 0; d0 < HD_DIM; d0 += 4) {
    float4 f = *reinterpret_cast<const float4*>(qrow + d0);
    q[d0] = f.x; q[d0 + 1] = f.y; q[d0 + 2] = f.z; q[d0 + 3] = f.w;
  }

  float O[HD_DIM];
#pragma unroll
  for (int d = 0; d < HD_DIM; ++d) O[d] = 0.0f;
  float mrun = -1e30f, lrun = 0.0f;

  __shared__ __align__(16) float Ks[64 * HD_DIM];
  __shared__ __align__(16) float Vs[64 * HD_DIM];

  for (int kt = 0; kt < T_DIM; kt += 64) {
    __syncthreads();   // previous tile fully consumed
    // stage K,V tile: 64 keys x 64 dims, float4, coalesced per wave
#pragma unroll
    for (int i = 0; i < 8; ++i) {
      int idx = i * 128 + threadIdx.x;      // 0..1023 float4 units
      int kr = idx >> 4;                    // key row 0..63
      int kc = (idx & 15) << 2;             // 0,4,...,60
      size_t g = ((size_t)(kt + kr) * B_DIM + b) * E_DIM + col0 + kc;
      *reinterpret_cast<float4*>(&Ks[kr * HD_DIM + kc]) = *reinterpret_cast<const float4*>(&kb[g]);
      *reinterpret_cast<float4*>(&Vs[kr * HD_DIM + kc]) = *reinterpret_cast<const float4*>(&vb[g]);
    }
    __syncthreads();

#pragma unroll 1
    for (int j = 0; j < 64; ++j) {
      // dot(q, K[j]) with 4 accumulators for ILP; Ks reads are uniform -> broadcast
      float s0 = 0.f, s1 = 0.f, s2 = 0.f, s3 = 0.f;
#pragma unroll
      for (int d = 0; d < HD_DIM; d += 4) {
        s0 += q[d + 0] * Ks[j * HD_DIM + d + 0];
        s1 += q[d + 1] * Ks[j * HD_DIM + d + 1];
        s2 += q[d + 2] * Ks[j * HD_DIM + d + 2];
        s3 += q[d + 3] * Ks[j * HD_DIM + d + 3];
      }
      float s = ((s0 + s1) + (s2 + s3)) * 0.125f;   // HD^-0.5

      if (s > mrun) {            // rare after warm-up; divergence acceptable
        float corr = __expf(mrun - s);
        lrun *= corr;
#pragma unroll
        for (int d = 0; d < HD_DIM; ++d) O[d] *= corr;
        mrun = s;
      }
      float p = __expf(s - mrun);
      lrun += p;
#pragma unroll
      for (int d = 0; d < HD_DIM; ++d) O[d] += p * Vs[j * HD_DIM + d];
    }
  }

  float inv = 1.0f / lrun;
  float* orow = ob + ((size_t)tq * B_DIM + b) * E_DIM + col0;
#pragma unroll
  for (int d0 = 0; d0 < HD_DIM; d0 += 4) {
    float4 f;
    f.x = O[d0] * inv; f.y = O[d0 + 1] * inv; f.z = O[d0 + 2] * inv; f.w = O[d0 + 3] * inv;
    *reinterpret_cast<float4*>(orow + d0) = f;
  }
}

// ---------------------------------------------------------------------------
extern "C" void kernel_launch(void* const* d_in, const int* in_sizes, int n_in,
                              void* d_out, int out_size, void* d_ws, size_t ws_size,
                              hipStream_t stream) {
  const float* query  = (const float*)d_in[0];
  // d_in[1] (key) and d_in[2] (value) are ignored by the reference module
  const float* mag_q  = (const float*)d_in[3];
  const float* dir_q  = (const float*)d_in[4];
  const float* A_q    = (const float*)d_in[5];
  const float* B_q    = (const float*)d_in[6];
  const float* bias_q = (const float*)d_in[7];
  const float* mag_v  = (const float*)d_in[8];
  const float* dir_v  = (const float*)d_in[9];
  const float* A_v    = (const float*)d_in[10];
  const float* B_v    = (const float*)d_in[11];
  const float* bias_v = (const float*)d_in[12];
  const float* k_w    = (const float*)d_in[13];
  const float* k_b    = (const float*)d_in[14];
  const float* out_w  = (const float*)d_in[15];
  const float* out_b  = (const float*)d_in[16];
  float* out = (float*)d_out;

  // workspace layout (all regions fully rewritten every call):
  //   partials: 512 f32, scales: 2 f32 (offset 4096B for alignment)
  //   Wq, Wv:   1024*1024 f32 each  (unscaled Vu)
  //   qbuf,kbuf,vbuf,abuf: 4096*1024 f32 each
  // total ~72 MB
  char* ws = (char*)d_ws;
  float* partials = (float*)ws;
  float* scales   = (float*)(ws + 2048);
  float* Wq   = (float*)(ws + 4096);
  float* Wv   = Wq + (size_t)E_DIM * E_DIM;
  float* qbuf = Wv + (size_t)E_DIM * E_DIM;
  float* kbuf = qbuf + (size_t)M_ROWS * E_DIM;
  float* vbuf = kbuf + (size_t)M_ROWS * E_DIM;
  float* abuf = vbuf + (size_t)M_ROWS * E_DIM;

  dora_pass1<<<dim3(256, 2), 256, 0, stream>>>(dir_q, A_q, B_q, dir_v, A_v, B_v, Wq, Wv, partials);
  dora_pass2<<<1, 256, 0, stream>>>(partials, mag_q, mag_v, scales);

  gemm_nt<<<dim3(64, 16), 256, 0, stream>>>(query, Wq,    bias_q, scales + 0, qbuf);
  gemm_nt<<<dim3(64, 16), 256, 0, stream>>>(query, k_w,   k_b,    nullptr,    kbuf);
  gemm_nt<<<dim3(64, 16), 256, 0, stream>>>(query, Wv,    bias_v, scales + 1, vbuf);

  attn_fp32<<<dim3(T_DIM / 128, B_DIM * H_DIM), 128, 0, stream>>>(qbuf, kbuf, vbuf, abuf);

  gemm_nt<<<dim3(64, 16), 256, 0, stream>>>(abuf, out_w, out_b, nullptr, out);
}

// Round 3
// 349.361 us; speedup vs baseline: 5.5430x; 5.5430x over previous
//
#include <hip/hip_runtime.h>
#include <hip/hip_bf16.h>

// Problem constants
#define E_DIM 1024
#define T_DIM 2048
#define B_DIM 2
#define H_DIM 16
#define HD_DIM 64
#define R_DIM 8
#define M_ROWS (T_DIM * B_DIM)   // 4096 rows for all projections

typedef __attribute__((ext_vector_type(8))) short bf16x8;   // 8 bf16 (4 VGPRs)
typedef __attribute__((ext_vector_type(4))) float f32x4;    // 4 fp32 acc

// round-to-nearest-even f32 -> bf16 (as raw ushort)
__device__ __forceinline__ unsigned short f2bf(float f) {
  unsigned int u = __builtin_bit_cast(unsigned int, f);
  u += 0x7FFFu + ((u >> 16) & 1u);
  return (unsigned short)(u >> 16);
}

// ---------------------------------------------------------------------------
// f32 -> bf16 bulk convert (float4 in, ushort4 out)
// ---------------------------------------------------------------------------
__global__ __launch_bounds__(256) void f32_to_bf16(
    const float* __restrict__ src, unsigned short* __restrict__ dst, int n4) {
  int i = blockIdx.x * 256 + threadIdx.x;
  if (i < n4) {
    float4 f = reinterpret_cast<const float4*>(src)[i];
    ushort4 o;
    o.x = f2bf(f.x); o.y = f2bf(f.y); o.z = f2bf(f.z); o.w = f2bf(f.w);
    reinterpret_cast<ushort4*>(dst)[i] = o;
  }
}

// ---------------------------------------------------------------------------
// Pass 1: Vu = dir + B@A  -> bf16 W, fp32 partial sums of Vu^2
// grid: (256, 2)  block: 256
// ---------------------------------------------------------------------------
__global__ __launch_bounds__(256) void dora_pass1(
    const float* __restrict__ dir_q, const float* __restrict__ A_q, const float* __restrict__ B_q,
    const float* __restrict__ dir_v, const float* __restrict__ A_v, const float* __restrict__ B_v,
    unsigned short* __restrict__ Wq, unsigned short* __restrict__ Wv,
    float* __restrict__ partials) {
  const int mat = blockIdx.y;
  const float* __restrict__ dir = mat ? dir_v : dir_q;
  const float* __restrict__ Am  = mat ? A_v   : A_q;
  const float* __restrict__ Bm  = mat ? B_v   : B_q;
  unsigned short* __restrict__ W = mat ? Wv : Wq;

  float sum = 0.0f;
  for (int idx = blockIdx.x * 256 + threadIdx.x; idx < E_DIM * E_DIM; idx += 256 * 256) {
    int i = idx >> 10;
    int j = idx & (E_DIM - 1);
    float v = dir[idx];
#pragma unroll
    for (int r = 0; r < R_DIM; ++r)
      v += Bm[i * R_DIM + r] * Am[r * E_DIM + j];
    W[idx] = f2bf(v);
    sum += v * v;           // norm computed on fp32 values (matches reference)
  }
#pragma unroll
  for (int off = 32; off > 0; off >>= 1) sum += __shfl_down(sum, off);
  __shared__ float red[4];
  if ((threadIdx.x & 63) == 0) red[threadIdx.x >> 6] = sum;
  __syncthreads();
  if (threadIdx.x == 0)
    partials[mat * 256 + blockIdx.x] = (red[0] + red[1]) + (red[2] + red[3]);
}

// ---------------------------------------------------------------------------
// Pass 2: scales[0]=m_q/(||Vu_q||+1e-8), scales[1]=m_v/(...), scales[2]=1.0
// ---------------------------------------------------------------------------
__global__ __launch_bounds__(256) void dora_pass2(
    const float* __restrict__ partials, const float* __restrict__ mag_q,
    const float* __restrict__ mag_v, float* __restrict__ scales) {
  __shared__ float red[4];
  for (int mat = 0; mat < 2; ++mat) {
    float s = partials[mat * 256 + threadIdx.x];
#pragma unroll
    for (int off = 32; off > 0; off >>= 1) s += __shfl_down(s, off);
    if ((threadIdx.x & 63) == 0) red[threadIdx.x >> 6] = s;
    __syncthreads();
    if (threadIdx.x == 0) {
      float tot = (red[0] + red[1]) + (red[2] + red[3]);
      float m = mat ? mag_v[0] : mag_q[0];
      scales[mat] = m / (sqrtf(tot) + 1e-8f);
    }
    __syncthreads();
  }
  if (threadIdx.x == 0) scales[2] = 1.0f;
}

// ---------------------------------------------------------------------------
// bf16 MFMA GEMM core (B^T input): C[4096,1024] = scale*(A @ W^T) + bscale*bias
// 128x128 tile, BK=32, 256 threads (4 waves 2x2), 4x4 fragment repeats/wave.
// Reg-staged global->LDS. Tile = 128 rows x 32 bf16 cols = 512 float4 units:
//   unit c -> row r = c>>2, bf16 col off = (c&3)*8 ; LDS addr c*8 = r*32+off.
// ---------------------------------------------------------------------------
template <int OUT_BF16>
__device__ __forceinline__ void gemm_bt_core(
    const unsigned short* __restrict__ A, const unsigned short* __restrict__ W,
    const float* __restrict__ bias, float scale, float bscale,
    void* __restrict__ Cptr, int bm, int bn) {
  __shared__ unsigned short As[128 * 32];
  __shared__ unsigned short Bs[128 * 32];
  const int tid = threadIdx.x;
  const int w = tid >> 6, lane = tid & 63;
  const int lr = lane & 15, lg = lane >> 4;
  const int wm = w >> 1, wn = w & 1;

  f32x4 acc[4][4];
#pragma unroll
  for (int i = 0; i < 4; ++i)
#pragma unroll
    for (int j = 0; j < 4; ++j) acc[i][j] = (f32x4){0.f, 0.f, 0.f, 0.f};

  float4 ra[2], rb[2];
#pragma unroll
  for (int it = 0; it < 2; ++it) {
    int c = it * 256 + tid, r = c >> 2, off = (c & 3) * 8;
    ra[it] = *reinterpret_cast<const float4*>(A + (size_t)(bm + r) * E_DIM + off);
    rb[it] = *reinterpret_cast<const float4*>(W + (size_t)(bn + r) * E_DIM + off);
  }

  for (int k0 = 0; k0 < E_DIM; k0 += 32) {
#pragma unroll
    for (int it = 0; it < 2; ++it) {
      int c = it * 256 + tid;
      *reinterpret_cast<float4*>(As + c * 8) = ra[it];
      *reinterpret_cast<float4*>(Bs + c * 8) = rb[it];
    }
    __syncthreads();
    if (k0 + 32 < E_DIM) {
#pragma unroll
      for (int it = 0; it < 2; ++it) {
        int c = it * 256 + tid, r = c >> 2, off = (c & 3) * 8;
        ra[it] = *reinterpret_cast<const float4*>(A + (size_t)(bm + r) * E_DIM + k0 + 32 + off);
        rb[it] = *reinterpret_cast<const float4*>(W + (size_t)(bn + r) * E_DIM + k0 + 32 + off);
      }
    }
    bf16x8 af[4], bf[4];
#pragma unroll
    for (int i = 0; i < 4; ++i)
      af[i] = *reinterpret_cast<const bf16x8*>(As + (wm * 64 + i * 16 + lr) * 32 + lg * 8);
#pragma unroll
    for (int j = 0; j < 4; ++j)
      bf[j] = *reinterpret_cast<const bf16x8*>(Bs + (wn * 64 + j * 16 + lr) * 32 + lg * 8);
#pragma unroll
    for (int i = 0; i < 4; ++i)
#pragma unroll
      for (int j = 0; j < 4; ++j)
        acc[i][j] = __builtin_amdgcn_mfma_f32_16x16x32_bf16(af[i], bf[j], acc[i][j], 0, 0, 0);
    __syncthreads();
  }

  // epilogue: C row = bm + wm*64 + i*16 + lg*4 + r ; col = bn + wn*64 + j*16 + lr
#pragma unroll
  for (int i = 0; i < 4; ++i) {
    int row = bm + wm * 64 + i * 16 + lg * 4;
#pragma unroll
    for (int j = 0; j < 4; ++j) {
      int col = bn + wn * 64 + j * 16 + lr;
      float bv = bias[col] * bscale;
#pragma unroll
      for (int r = 0; r < 4; ++r) {
        float v = scale * acc[i][j][r] + bv;
        if (OUT_BF16)
          reinterpret_cast<unsigned short*>(Cptr)[(size_t)(row + r) * E_DIM + col] = f2bf(v);
        else
          reinterpret_cast<float*>(Cptr)[(size_t)(row + r) * E_DIM + col] = v;
      }
    }
  }
}

// Fused QKV projection: grid (32, 24); blockIdx.y>>3 selects {q,k,v}
__global__ __launch_bounds__(256) void gemm_qkv(
    const unsigned short* __restrict__ Abf,
    const unsigned short* __restrict__ Wq, const unsigned short* __restrict__ Wk,
    const unsigned short* __restrict__ Wv,
    const float* __restrict__ bias_q, const float* __restrict__ k_b,
    const float* __restrict__ bias_v, const float* __restrict__ scales,
    unsigned short* __restrict__ qbuf, unsigned short* __restrict__ kbuf,
    unsigned short* __restrict__ vbuf) {
  const int mat = blockIdx.y >> 3;
  const int bm = blockIdx.x * 128, bn = (blockIdx.y & 7) * 128;
  const unsigned short* W = (mat == 0) ? Wq : (mat == 1) ? Wk : Wv;
  const float* bias = (mat == 0) ? bias_q : (mat == 1) ? k_b : bias_v;
  unsigned short* out = (mat == 0) ? qbuf : (mat == 1) ? kbuf : vbuf;
  // fold softmax scale 2^-3 (exact) into q projection (matmul AND bias)
  float smul = (mat == 0) ? 0.125f : 1.0f;
  float scale = ((mat == 0) ? scales[0] : (mat == 1) ? scales[2] : scales[1]) * smul;
  gemm_bt_core<1>(Abf, W, bias, scale, smul, out, bm, bn);
}

// Output projection: bf16 in, f32 out
__global__ __launch_bounds__(256) void gemm_out(
    const unsigned short* __restrict__ Abf, const unsigned short* __restrict__ Wo,
    const float* __restrict__ bias, float* __restrict__ out) {
  gemm_bt_core<0>(Abf, Wo, bias, 1.0f, 1.0f, out, blockIdx.x * 128, blockIdx.y * 128);
}

// ---------------------------------------------------------------------------
// Flash attention, bf16 MFMA. Block = 256 threads (4 waves), Q-tile 128 rows
// (32/wave), KV-tile 64. K staged [64][72] row-major, V staged transposed
// [64d][72k], P round-trip via per-wave LDS [32][72]. Scores pre-scaled
// (0.125 folded into q projection).
// grid: (T/128, B*H)
// ---------------------------------------------------------------------------
#define LDP 72   // padded LDS leading dim (16B-aligned rows)

__global__ __launch_bounds__(256) void attn_mfma(
    const unsigned short* __restrict__ qb, const unsigned short* __restrict__ kb,
    const unsigned short* __restrict__ vb, unsigned short* __restrict__ ob) {
  __shared__ unsigned short Ks[64 * LDP];
  __shared__ unsigned short Vt[64 * LDP];
  __shared__ unsigned short Ps[4][32 * LDP];
  const int n = blockIdx.y, b = n >> 4, h = n & 15, col0 = h * HD_DIM;
  const int tid = threadIdx.x, w = tid >> 6, lane = tid & 63;
  const int lr = lane & 15, lg = lane >> 4;
  const int q0 = blockIdx.x * 128 + w * 32;
  unsigned short* Pw = Ps[w];

  // Q fragments (A-operand), resident whole kernel
  bf16x8 qf[2][2];
#pragma unroll
  for (int rf = 0; rf < 2; ++rf)
#pragma unroll
    for (int ks = 0; ks < 2; ++ks) {
      int row = q0 + rf * 16 + lr;
      qf[rf][ks] = *reinterpret_cast<const bf16x8*>(
          qb + ((size_t)row * B_DIM + b) * E_DIM + col0 + ks * 32 + lg * 8);
    }

  f32x4 accO[2][4];
  float mrun[2][4], lrun[2][4];
#pragma unroll
  for (int rf = 0; rf < 2; ++rf)
#pragma unroll
    for (int i = 0; i < 4; ++i) {
      accO[rf][i] = (f32x4){0.f, 0.f, 0.f, 0.f};
      mrun[rf][i] = -1e30f; lrun[rf][i] = 0.f;
    }

  for (int kt = 0; kt < T_DIM; kt += 64) {
    __syncthreads();   // previous tile's PV fully consumed
    // stage K row-major + V transposed (64 rows x 64 cols = 512 float4 units)
#pragma unroll
    for (int it = 0; it < 2; ++it) {
      int c = it * 256 + tid, r = c >> 3, c0 = (c & 7) * 8;
      size_t g = ((size_t)(kt + r) * B_DIM + b) * E_DIM + col0 + c0;
      float4 kk = *reinterpret_cast<const float4*>(kb + g);
      *reinterpret_cast<float4*>(Ks + r * LDP + c0) = kk;
      float4 vv = *reinterpret_cast<const float4*>(vb + g);
      unsigned short tmp[8];
      *reinterpret_cast<float4*>(tmp) = vv;
#pragma unroll
      for (int i2 = 0; i2 < 8; ++i2) Vt[(c0 + i2) * LDP + r] = tmp[i2];
    }
    __syncthreads();

    // S = Q K^T (already scaled by HD^-0.5 via q)
    f32x4 s[2][4];
#pragma unroll
    for (int rf = 0; rf < 2; ++rf)
#pragma unroll
      for (int kf = 0; kf < 4; ++kf) s[rf][kf] = (f32x4){0.f, 0.f, 0.f, 0.f};
#pragma unroll
    for (int ks = 0; ks < 2; ++ks)
#pragma unroll
      for (int kf = 0; kf < 4; ++kf) {
        bf16x8 kfr = *reinterpret_cast<const bf16x8*>(Ks + (kf * 16 + lr) * LDP + ks * 32 + lg * 8);
#pragma unroll
        for (int rf = 0; rf < 2; ++rf)
          s[rf][kf] = __builtin_amdgcn_mfma_f32_16x16x32_bf16(qf[rf][ks], kfr, s[rf][kf], 0, 0, 0);
      }

    // online softmax (rows = lg*4+r per rf; reduce across lr via shfl_xor)
    float alpha[2][4];
#pragma unroll
    for (int rf = 0; rf < 2; ++rf)
#pragma unroll
      for (int r = 0; r < 4; ++r) {
        float pm = fmaxf(fmaxf(s[rf][0][r], s[rf][1][r]), fmaxf(s[rf][2][r], s[rf][3][r]));
#pragma unroll
        for (int m2 = 1; m2 < 16; m2 <<= 1) pm = fmaxf(pm, __shfl_xor(pm, m2));
        float mnew = fmaxf(mrun[rf][r], pm);
        float al = __expf(mrun[rf][r] - mnew);
        mrun[rf][r] = mnew; alpha[rf][r] = al;
        float psum = 0.f;
#pragma unroll
        for (int kf = 0; kf < 4; ++kf) {
          float p = __expf(s[rf][kf][r] - mnew);
          s[rf][kf][r] = p; psum += p;
        }
#pragma unroll
        for (int m2 = 1; m2 < 16; m2 <<= 1) psum += __shfl_xor(psum, m2);
        lrun[rf][r] = lrun[rf][r] * al + psum;
      }

    // P -> per-wave LDS (C-layout -> A-fragment layout round-trip)
#pragma unroll
    for (int rf = 0; rf < 2; ++rf)
#pragma unroll
      for (int kf = 0; kf < 4; ++kf)
#pragma unroll
        for (int r = 0; r < 4; ++r)
          Pw[(rf * 16 + lg * 4 + r) * LDP + kf * 16 + lr] = f2bf(s[rf][kf][r]);

    // rescale O
#pragma unroll
    for (int rf = 0; rf < 2; ++rf)
#pragma unroll
      for (int df = 0; df < 4; ++df)
#pragma unroll
        for (int r = 0; r < 4; ++r) accO[rf][df][r] *= alpha[rf][r];

    // O += P V  (Pw per-wave private: same-wave LDS writes/reads are ordered)
#pragma unroll
    for (int ks = 0; ks < 2; ++ks) {
      bf16x8 pf0 = *reinterpret_cast<const bf16x8*>(Pw + lr * LDP + ks * 32 + lg * 8);
      bf16x8 pf1 = *reinterpret_cast<const bf16x8*>(Pw + (16 + lr) * LDP + ks * 32 + lg * 8);
#pragma unroll
      for (int df = 0; df < 4; ++df) {
        bf16x8 vf = *reinterpret_cast<const bf16x8*>(Vt + (df * 16 + lr) * LDP + ks * 32 + lg * 8);
        accO[0][df] = __builtin_amdgcn_mfma_f32_16x16x32_bf16(pf0, vf, accO[0][df], 0, 0, 0);
        accO[1][df] = __builtin_amdgcn_mfma_f32_16x16x32_bf16(pf1, vf, accO[1][df], 0, 0, 0);
      }
    }
  }

  // normalize + write bf16
#pragma unroll
  for (int rf = 0; rf < 2; ++rf)
#pragma unroll
    for (int r = 0; r < 4; ++r) {
      float inv = 1.0f / lrun[rf][r];
      int row = q0 + rf * 16 + lg * 4 + r;
      size_t base = ((size_t)row * B_DIM + b) * E_DIM + col0;
#pragma unroll
      for (int df = 0; df < 4; ++df)
        ob[base + df * 16 + lr] = f2bf(accO[rf][df][r] * inv);
    }
}

// ---------------------------------------------------------------------------
extern "C" void kernel_launch(void* const* d_in, const int* in_sizes, int n_in,
                              void* d_out, int out_size, void* d_ws, size_t ws_size,
                              hipStream_t stream) {
  const float* query  = (const float*)d_in[0];
  const float* mag_q  = (const float*)d_in[3];
  const float* dir_q  = (const float*)d_in[4];
  const float* A_q    = (const float*)d_in[5];
  const float* B_q    = (const float*)d_in[6];
  const float* bias_q = (const float*)d_in[7];
  const float* mag_v  = (const float*)d_in[8];
  const float* dir_v  = (const float*)d_in[9];
  const float* A_v    = (const float*)d_in[10];
  const float* B_v    = (const float*)d_in[11];
  const float* bias_v = (const float*)d_in[12];
  const float* k_w    = (const float*)d_in[13];
  const float* k_b    = (const float*)d_in[14];
  const float* out_w  = (const float*)d_in[15];
  const float* out_b  = (const float*)d_in[16];
  float* out = (float*)d_out;

  // workspace layout (~48 MB, all regions fully rewritten every call)
  char* ws = (char*)d_ws;
  float* partials = (float*)ws;                          // 2048 B
  float* scales   = (float*)(ws + 2048);                 // 3 f32
  unsigned short* qA_bf = (unsigned short*)(ws + 4096);  // query bf16, 8 MB
  unsigned short* wq_bf = qA_bf + (size_t)M_ROWS * E_DIM;
  unsigned short* wv_bf = wq_bf + (size_t)E_DIM * E_DIM;
  unsigned short* kw_bf = wv_bf + (size_t)E_DIM * E_DIM;
  unsigned short* ow_bf = kw_bf + (size_t)E_DIM * E_DIM;
  unsigned short* qbuf  = ow_bf + (size_t)E_DIM * E_DIM;
  unsigned short* kbuf  = qbuf + (size_t)M_ROWS * E_DIM;
  unsigned short* vbuf  = kbuf + (size_t)M_ROWS * E_DIM;
  unsigned short* abuf  = vbuf + (size_t)M_ROWS * E_DIM;

  f32_to_bf16<<<4096, 256, 0, stream>>>(query, qA_bf, M_ROWS * E_DIM / 4);
  f32_to_bf16<<<1024, 256, 0, stream>>>(k_w, kw_bf, E_DIM * E_DIM / 4);
  f32_to_bf16<<<1024, 256, 0, stream>>>(out_w, ow_bf, E_DIM * E_DIM / 4);
  dora_pass1<<<dim3(256, 2), 256, 0, stream>>>(dir_q, A_q, B_q, dir_v, A_v, B_v,
                                               wq_bf, wv_bf, partials);
  dora_pass2<<<1, 256, 0, stream>>>(partials, mag_q, mag_v, scales);

  gemm_qkv<<<dim3(32, 24), 256, 0, stream>>>(qA_bf, wq_bf, kw_bf, wv_bf,
                                             bias_q, k_b, bias_v, scales,
                                             qbuf, kbuf, vbuf);
  attn_mfma<<<dim3(T_DIM / 128, B_DIM * H_DIM), 256, 0, stream>>>(qbuf, kbuf, vbuf, abuf);
  gemm_out<<<dim3(32, 8), 256, 0, stream>>>(abuf, ow_bf, out_b, out);
}

// Round 4
// 291.381 us; speedup vs baseline: 6.6459x; 1.1990x over previous
//
#include <hip/hip_runtime.h>
#include <hip/hip_bf16.h>

// Problem constants
#define E_DIM 1024
#define T_DIM 2048
#define B_DIM 2
#define H_DIM 16
#define HD_DIM 64
#define R_DIM 8
#define M_ROWS (T_DIM * B_DIM)   // 4096 rows for all projections

typedef __attribute__((ext_vector_type(8))) short bf16x8;   // 8 bf16 (4 VGPRs)
typedef __attribute__((ext_vector_type(4))) float f32x4;    // 4 fp32 acc

// round-to-nearest-even f32 -> bf16 (as raw ushort)
__device__ __forceinline__ unsigned short f2bf(float f) {
  unsigned int u = __builtin_bit_cast(unsigned int, f);
  u += 0x7FFFu + ((u >> 16) & 1u);
  return (unsigned short)(u >> 16);
}

// ---------------------------------------------------------------------------
// f32 -> bf16 bulk convert
// ---------------------------------------------------------------------------
__global__ __launch_bounds__(256) void f32_to_bf16(
    const float* __restrict__ src, unsigned short* __restrict__ dst, int n4) {
  int i = blockIdx.x * 256 + threadIdx.x;
  if (i < n4) {
    float4 f = reinterpret_cast<const float4*>(src)[i];
    ushort4 o;
    o.x = f2bf(f.x); o.y = f2bf(f.y); o.z = f2bf(f.z); o.w = f2bf(f.w);
    reinterpret_cast<ushort4*>(dst)[i] = o;
  }
}

// ---------------------------------------------------------------------------
// Pass 1: Vu = dir + B@A -> bf16 W, fp32 partial sums of Vu^2
// ---------------------------------------------------------------------------
__global__ __launch_bounds__(256) void dora_pass1(
    const float* __restrict__ dir_q, const float* __restrict__ A_q, const float* __restrict__ B_q,
    const float* __restrict__ dir_v, const float* __restrict__ A_v, const float* __restrict__ B_v,
    unsigned short* __restrict__ Wq, unsigned short* __restrict__ Wv,
    float* __restrict__ partials) {
  const int mat = blockIdx.y;
  const float* __restrict__ dir = mat ? dir_v : dir_q;
  const float* __restrict__ Am  = mat ? A_v   : A_q;
  const float* __restrict__ Bm  = mat ? B_v   : B_q;
  unsigned short* __restrict__ W = mat ? Wv : Wq;

  float sum = 0.0f;
  for (int idx = blockIdx.x * 256 + threadIdx.x; idx < E_DIM * E_DIM; idx += 256 * 256) {
    int i = idx >> 10;
    int j = idx & (E_DIM - 1);
    float v = dir[idx];
#pragma unroll
    for (int r = 0; r < R_DIM; ++r)
      v += Bm[i * R_DIM + r] * Am[r * E_DIM + j];
    W[idx] = f2bf(v);
    sum += v * v;
  }
#pragma unroll
  for (int off = 32; off > 0; off >>= 1) sum += __shfl_down(sum, off);
  __shared__ float red[4];
  if ((threadIdx.x & 63) == 0) red[threadIdx.x >> 6] = sum;
  __syncthreads();
  if (threadIdx.x == 0)
    partials[mat * 256 + blockIdx.x] = (red[0] + red[1]) + (red[2] + red[3]);
}

// ---------------------------------------------------------------------------
// Pass 2: scales[0]=m_q/(||Vu_q||+1e-8), scales[1]=m_v/(...), scales[2]=1.0
// ---------------------------------------------------------------------------
__global__ __launch_bounds__(256) void dora_pass2(
    const float* __restrict__ partials, const float* __restrict__ mag_q,
    const float* __restrict__ mag_v, float* __restrict__ scales) {
  __shared__ float red[4];
  for (int mat = 0; mat < 2; ++mat) {
    float s = partials[mat * 256 + threadIdx.x];
#pragma unroll
    for (int off = 32; off > 0; off >>= 1) s += __shfl_down(s, off);
    if ((threadIdx.x & 63) == 0) red[threadIdx.x >> 6] = s;
    __syncthreads();
    if (threadIdx.x == 0) {
      float tot = (red[0] + red[1]) + (red[2] + red[3]);
      float m = mat ? mag_v[0] : mag_q[0];
      scales[mat] = m / (sqrtf(tot) + 1e-8f);
    }
    __syncthreads();
  }
  if (threadIdx.x == 0) scales[2] = 1.0f;
}

// ---------------------------------------------------------------------------
// bf16 MFMA GEMM core: C = scale*(A @ W^T) + bias. 128x128 tile, BK=32,
// 256 thr (4 waves 2x2), 4x4 frags/wave, reg-staged global->LDS.
// OUT_MODE: 0 = f32 C[row][col]; 1 = bf16 C[row][col];
//           2 = bf16 V^T scatter vT[b][h][d][t], bias indexed by A-row.
// ---------------------------------------------------------------------------
template <int OUT_MODE>
__device__ __forceinline__ void gemm_bt_core(
    const unsigned short* __restrict__ A, const unsigned short* __restrict__ W,
    const float* __restrict__ bias, float scale, float bscale,
    void* __restrict__ Cptr, int bm, int bn) {
  __shared__ unsigned short As[128 * 32];
  __shared__ unsigned short Bs[128 * 32];
  const int tid = threadIdx.x;
  const int w = tid >> 6, lane = tid & 63;
  const int lr = lane & 15, lg = lane >> 4;
  const int wm = w >> 1, wn = w & 1;

  f32x4 acc[4][4];
#pragma unroll
  for (int i = 0; i < 4; ++i)
#pragma unroll
    for (int j = 0; j < 4; ++j) acc[i][j] = (f32x4){0.f, 0.f, 0.f, 0.f};

  float4 ra[2], rb[2];
#pragma unroll
  for (int it = 0; it < 2; ++it) {
    int c = it * 256 + tid, r = c >> 2, off = (c & 3) * 8;
    ra[it] = *reinterpret_cast<const float4*>(A + (size_t)(bm + r) * E_DIM + off);
    rb[it] = *reinterpret_cast<const float4*>(W + (size_t)(bn + r) * E_DIM + off);
  }

  for (int k0 = 0; k0 < E_DIM; k0 += 32) {
#pragma unroll
    for (int it = 0; it < 2; ++it) {
      int c = it * 256 + tid;
      *reinterpret_cast<float4*>(As + c * 8) = ra[it];
      *reinterpret_cast<float4*>(Bs + c * 8) = rb[it];
    }
    __syncthreads();
    if (k0 + 32 < E_DIM) {
#pragma unroll
      for (int it = 0; it < 2; ++it) {
        int c = it * 256 + tid, r = c >> 2, off = (c & 3) * 8;
        ra[it] = *reinterpret_cast<const float4*>(A + (size_t)(bm + r) * E_DIM + k0 + 32 + off);
        rb[it] = *reinterpret_cast<const float4*>(W + (size_t)(bn + r) * E_DIM + k0 + 32 + off);
      }
    }
    bf16x8 af[4], bf[4];
#pragma unroll
    for (int i = 0; i < 4; ++i)
      af[i] = *reinterpret_cast<const bf16x8*>(As + (wm * 64 + i * 16 + lr) * 32 + lg * 8);
#pragma unroll
    for (int j = 0; j < 4; ++j)
      bf[j] = *reinterpret_cast<const bf16x8*>(Bs + (wn * 64 + j * 16 + lr) * 32 + lg * 8);
#pragma unroll
    for (int i = 0; i < 4; ++i)
#pragma unroll
      for (int j = 0; j < 4; ++j)
        acc[i][j] = __builtin_amdgcn_mfma_f32_16x16x32_bf16(af[i], bf[j], acc[i][j], 0, 0, 0);
    __syncthreads();
  }

  if (OUT_MODE == 2) {
    // C^T scatter: A-row = V out-col (wrow), W-row = token row (xrow).
#pragma unroll
    for (int i = 0; i < 4; ++i) {
      int rowbase = bm + wm * 64 + i * 16 + lg * 4;
      float4 bb = *reinterpret_cast<const float4*>(&bias[rowbase]);
      float bbv[4] = {bb.x, bb.y, bb.z, bb.w};
#pragma unroll
      for (int j = 0; j < 4; ++j) {
        int xrow = bn + wn * 64 + j * 16 + lr;
        int t = xrow >> 1, bsel = xrow & 1;
#pragma unroll
        for (int rr = 0; rr < 4; ++rr) {
          int wrow = rowbase + rr;
          float v = scale * acc[i][j][rr] + bbv[rr];
          int nn = (bsel << 4) | (wrow >> 6);
          int d = wrow & 63;
          reinterpret_cast<unsigned short*>(Cptr)[((size_t)nn * HD_DIM + d) * T_DIM + t] = f2bf(v);
        }
      }
    }
  } else {
#pragma unroll
    for (int i = 0; i < 4; ++i) {
      int row = bm + wm * 64 + i * 16 + lg * 4;
#pragma unroll
      for (int j = 0; j < 4; ++j) {
        int col = bn + wn * 64 + j * 16 + lr;
        float bv = bias[col] * bscale;
#pragma unroll
        for (int r = 0; r < 4; ++r) {
          float v = scale * acc[i][j][r] + bv;
          if (OUT_MODE == 1)
            reinterpret_cast<unsigned short*>(Cptr)[(size_t)(row + r) * E_DIM + col] = f2bf(v);
          else
            reinterpret_cast<float*>(Cptr)[(size_t)(row + r) * E_DIM + col] = v;
        }
      }
    }
  }
}

// Q + K projections: grid (32, 16); blockIdx.y>>3 selects {q,k}
__global__ __launch_bounds__(256) void gemm_qk(
    const unsigned short* __restrict__ Abf,
    const unsigned short* __restrict__ Wq, const unsigned short* __restrict__ Wk,
    const float* __restrict__ bias_q, const float* __restrict__ k_b,
    const float* __restrict__ scales,
    unsigned short* __restrict__ qbuf, unsigned short* __restrict__ kbuf) {
  const int mat = blockIdx.y >> 3;
  const int bm = blockIdx.x * 128, bn = (blockIdx.y & 7) * 128;
  if (mat == 0) {
    // fold softmax scale 2^-3 (exact) into q projection (matmul AND bias)
    gemm_bt_core<1>(Abf, Wq, bias_q, scales[0] * 0.125f, 0.125f, qbuf, bm, bn);
  } else {
    gemm_bt_core<1>(Abf, Wk, k_b, 1.0f, 1.0f, kbuf, bm, bn);
  }
}

// V projection producing V^T directly: A = Wv (1024 rows), W = x (4096 rows)
// grid (8, 32)
__global__ __launch_bounds__(256) void gemm_vT(
    const unsigned short* __restrict__ Wv, const unsigned short* __restrict__ xbf,
    const float* __restrict__ bias_v, const float* __restrict__ scales,
    unsigned short* __restrict__ vT) {
  gemm_bt_core<2>(Wv, xbf, bias_v, scales[1], 1.0f, vT, blockIdx.x * 128, blockIdx.y * 128);
}

// Output projection: bf16 in, f32 out
__global__ __launch_bounds__(256) void gemm_out(
    const unsigned short* __restrict__ Abf, const unsigned short* __restrict__ Wo,
    const float* __restrict__ bias, float* __restrict__ out) {
  gemm_bt_core<0>(Abf, Wo, bias, 1.0f, 1.0f, out, blockIdx.x * 128, blockIdx.y * 128);
}

// ---------------------------------------------------------------------------
// Flash attention, bf16 MFMA, swapped QK^T (S^T layout -> lane-local softmax).
// 4 waves x 32 q-rows, KV-tile 64. K row-major [64][72]; V staged from vT
// global (already transposed) [64d][72k]; P packed-dword round trip via
// per-wave LDS. alpha/l broadcast via 32-entry per-wave LDS arrays.
// grid: (T/128, B*H)
// ---------------------------------------------------------------------------
#define LDP 72

__global__ __launch_bounds__(256) void attn_mfma(
    const unsigned short* __restrict__ qb, const unsigned short* __restrict__ kb,
    const unsigned short* __restrict__ vT, unsigned short* __restrict__ ob) {
  __shared__ unsigned short Ks[64 * LDP];
  __shared__ unsigned short Vt[64 * LDP];
  __shared__ unsigned short Ps[4][32 * LDP];
  __shared__ float Aw[4][32];
  __shared__ float Lw[4][32];
  const int n = blockIdx.y, b = n >> 4, col0 = (n & 15) * HD_DIM;
  const int tid = threadIdx.x, w = tid >> 6, lane = tid & 63;
  const int lr = lane & 15, lg = lane >> 4;
  const int q0 = blockIdx.x * 128 + w * 32;
  unsigned short* Pw = Ps[w];

  // Q fragments, resident whole kernel
  bf16x8 qf[2][2];
#pragma unroll
  for (int rf = 0; rf < 2; ++rf)
#pragma unroll
    for (int ks = 0; ks < 2; ++ks)
      qf[rf][ks] = *reinterpret_cast<const bf16x8*>(
          qb + ((size_t)(q0 + rf * 16 + lr) * B_DIM + b) * E_DIM + col0 + ks * 32 + lg * 8);

  f32x4 accO[2][4];
#pragma unroll
  for (int rf = 0; rf < 2; ++rf)
#pragma unroll
    for (int df = 0; df < 4; ++df) accO[rf][df] = (f32x4){0.f, 0.f, 0.f, 0.f};
  float mrun0 = -1e30f, mrun1 = -1e30f, lrun0 = 0.f, lrun1 = 0.f;

  // staging decomposition (per thread, 2 float4 units each for K and V)
  const int sr0 = tid >> 3, sc0 = (tid & 7) * 8;          // it=0: rows 0..31
  const int sr1 = (256 + tid) >> 3;                        // it=1: rows 32..63
  float4 rk[2], rv[2];
  {
    rk[0] = *reinterpret_cast<const float4*>(kb + ((size_t)sr0 * B_DIM + b) * E_DIM + col0 + sc0);
    rk[1] = *reinterpret_cast<const float4*>(kb + ((size_t)sr1 * B_DIM + b) * E_DIM + col0 + sc0);
    rv[0] = *reinterpret_cast<const float4*>(vT + ((size_t)n * HD_DIM + sr0) * T_DIM + sc0);
    rv[1] = *reinterpret_cast<const float4*>(vT + ((size_t)n * HD_DIM + sr1) * T_DIM + sc0);
  }

  for (int kt = 0; kt < T_DIM; kt += 64) {
    __syncthreads();   // all waves done reading previous tile
    *reinterpret_cast<float4*>(Ks + sr0 * LDP + sc0) = rk[0];
    *reinterpret_cast<float4*>(Ks + sr1 * LDP + sc0) = rk[1];
    *reinterpret_cast<float4*>(Vt + sr0 * LDP + sc0) = rv[0];
    *reinterpret_cast<float4*>(Vt + sr1 * LDP + sc0) = rv[1];
    __syncthreads();
    if (kt + 64 < T_DIM) {   // prefetch next tile; hides under compute
      int kt2 = kt + 64;
      rk[0] = *reinterpret_cast<const float4*>(kb + ((size_t)(kt2 + sr0) * B_DIM + b) * E_DIM + col0 + sc0);
      rk[1] = *reinterpret_cast<const float4*>(kb + ((size_t)(kt2 + sr1) * B_DIM + b) * E_DIM + col0 + sc0);
      rv[0] = *reinterpret_cast<const float4*>(vT + ((size_t)n * HD_DIM + sr0) * T_DIM + kt2 + sc0);
      rv[1] = *reinterpret_cast<const float4*>(vT + ((size_t)n * HD_DIM + sr1) * T_DIM + kt2 + sc0);
    }

    // S^T = K Q^T : s[kf][rf]; lane holds q = q0+rf*16+lr, k = kf*16+lg*4+r
    f32x4 s[4][2];
#pragma unroll
    for (int kf = 0; kf < 4; ++kf)
#pragma unroll
      for (int rf = 0; rf < 2; ++rf) s[kf][rf] = (f32x4){0.f, 0.f, 0.f, 0.f};
#pragma unroll
    for (int ks = 0; ks < 2; ++ks)
#pragma unroll
      for (int kf = 0; kf < 4; ++kf) {
        bf16x8 kfr = *reinterpret_cast<const bf16x8*>(Ks + (kf * 16 + lr) * LDP + ks * 32 + lg * 8);
#pragma unroll
        for (int rf = 0; rf < 2; ++rf)
          s[kf][rf] = __builtin_amdgcn_mfma_f32_16x16x32_bf16(kfr, qf[rf][ks], s[kf][rf], 0, 0, 0);
      }

    // lane-local online softmax (16 in-lane k values + 2 shfl_xor)
    float al0, al1;
#pragma unroll
    for (int rf = 0; rf < 2; ++rf) {
      float pm = s[0][rf][0];
#pragma unroll
      for (int kf = 0; kf < 4; ++kf)
#pragma unroll
        for (int r = 0; r < 4; ++r) pm = fmaxf(pm, s[kf][rf][r]);
      pm = fmaxf(pm, __shfl_xor(pm, 16));
      pm = fmaxf(pm, __shfl_xor(pm, 32));
      float mold = rf ? mrun1 : mrun0;
      float mnew = fmaxf(mold, pm);
      float al = __expf(mold - mnew);
      float psum = 0.f;
#pragma unroll
      for (int kf = 0; kf < 4; ++kf)
#pragma unroll
        for (int r = 0; r < 4; ++r) {
          float p = __expf(s[kf][rf][r] - mnew);
          s[kf][rf][r] = p; psum += p;
        }
      psum += __shfl_xor(psum, 16);
      psum += __shfl_xor(psum, 32);
      if (rf) { mrun1 = mnew; lrun1 = lrun1 * al + psum; al1 = al; }
      else    { mrun0 = mnew; lrun0 = lrun0 * al + psum; al0 = al; }
    }
    // broadcast alpha by q-row (lanes lg==0 -> rf0, lg==1 -> rf1)
    if (lg < 2) Aw[w][lg * 16 + lr] = (lg == 0) ? al0 : al1;

    // P -> Pw, packed (q-row = rf*16+lr, k = kf*16+lg*4+{0..3})
#pragma unroll
    for (int rf = 0; rf < 2; ++rf)
#pragma unroll
      for (int kf = 0; kf < 4; ++kf) {
        uint2 pk;
        pk.x = (unsigned)f2bf(s[kf][rf][0]) | ((unsigned)f2bf(s[kf][rf][1]) << 16);
        pk.y = (unsigned)f2bf(s[kf][rf][2]) | ((unsigned)f2bf(s[kf][rf][3]) << 16);
        *reinterpret_cast<uint2*>(Pw + (rf * 16 + lr) * LDP + kf * 16 + lg * 4) = pk;
      }

    // rescale accO by alpha of its q-row (broadcast reads)
#pragma unroll
    for (int rf = 0; rf < 2; ++rf)
#pragma unroll
      for (int r = 0; r < 4; ++r) {
        float a = Aw[w][rf * 16 + lg * 4 + r];
#pragma unroll
        for (int df = 0; df < 4; ++df) accO[rf][df][r] *= a;
      }

    // O += P V (per-wave Pw: in-order LDS pipe, no barrier)
#pragma unroll
    for (int ks = 0; ks < 2; ++ks) {
      bf16x8 pa0 = *reinterpret_cast<const bf16x8*>(Pw + lr * LDP + ks * 32 + lg * 8);
      bf16x8 pa1 = *reinterpret_cast<const bf16x8*>(Pw + (16 + lr) * LDP + ks * 32 + lg * 8);
#pragma unroll
      for (int df = 0; df < 4; ++df) {
        bf16x8 vf = *reinterpret_cast<const bf16x8*>(Vt + (df * 16 + lr) * LDP + ks * 32 + lg * 8);
        accO[0][df] = __builtin_amdgcn_mfma_f32_16x16x32_bf16(pa0, vf, accO[0][df], 0, 0, 0);
        accO[1][df] = __builtin_amdgcn_mfma_f32_16x16x32_bf16(pa1, vf, accO[1][df], 0, 0, 0);
      }
    }
  }

  // broadcast lrun by q-row, normalize, write bf16
  if (lg < 2) Lw[w][lg * 16 + lr] = (lg == 0) ? lrun0 : lrun1;
#pragma unroll
  for (int rf = 0; rf < 2; ++rf)
#pragma unroll
    for (int r = 0; r < 4; ++r) {
      float inv = 1.0f / Lw[w][rf * 16 + lg * 4 + r];
      int row = q0 + rf * 16 + lg * 4 + r;
      size_t base = ((size_t)row * B_DIM + b) * E_DIM + col0;
#pragma unroll
      for (int df = 0; df < 4; ++df)
        ob[base + df * 16 + lr] = f2bf(accO[rf][df][r] * inv);
    }
}

// ---------------------------------------------------------------------------
extern "C" void kernel_launch(void* const* d_in, const int* in_sizes, int n_in,
                              void* d_out, int out_size, void* d_ws, size_t ws_size,
                              hipStream_t stream) {
  const float* query  = (const float*)d_in[0];
  const float* mag_q  = (const float*)d_in[3];
  const float* dir_q  = (const float*)d_in[4];
  const float* A_q    = (const float*)d_in[5];
  const float* B_q    = (const float*)d_in[6];
  const float* bias_q = (const float*)d_in[7];
  const float* mag_v  = (const float*)d_in[8];
  const float* dir_v  = (const float*)d_in[9];
  const float* A_v    = (const float*)d_in[10];
  const float* B_v    = (const float*)d_in[11];
  const float* bias_v = (const float*)d_in[12];
  const float* k_w    = (const float*)d_in[13];
  const float* k_b    = (const float*)d_in[14];
  const float* out_w  = (const float*)d_in[15];
  const float* out_b  = (const float*)d_in[16];
  float* out = (float*)d_out;

  // workspace layout (~48 MB, all regions fully rewritten every call)
  char* ws = (char*)d_ws;
  float* partials = (float*)ws;                          // 2048 B
  float* scales   = (float*)(ws + 2048);                 // 3 f32
  unsigned short* qA_bf = (unsigned short*)(ws + 4096);  // query bf16, 8 MB
  unsigned short* wq_bf = qA_bf + (size_t)M_ROWS * E_DIM;
  unsigned short* wv_bf = wq_bf + (size_t)E_DIM * E_DIM;
  unsigned short* kw_bf = wv_bf + (size_t)E_DIM * E_DIM;
  unsigned short* ow_bf = kw_bf + (size_t)E_DIM * E_DIM;
  unsigned short* qbuf  = ow_bf + (size_t)E_DIM * E_DIM;
  unsigned short* kbuf  = qbuf + (size_t)M_ROWS * E_DIM;
  unsigned short* vTbuf = kbuf + (size_t)M_ROWS * E_DIM;  // [b][h][d][t]
  unsigned short* abuf  = vTbuf + (size_t)M_ROWS * E_DIM;

  f32_to_bf16<<<4096, 256, 0, stream>>>(query, qA_bf, M_ROWS * E_DIM / 4);
  f32_to_bf16<<<1024, 256, 0, stream>>>(k_w, kw_bf, E_DIM * E_DIM / 4);
  f32_to_bf16<<<1024, 256, 0, stream>>>(out_w, ow_bf, E_DIM * E_DIM / 4);
  dora_pass1<<<dim3(256, 2), 256, 0, stream>>>(dir_q, A_q, B_q, dir_v, A_v, B_v,
                                               wq_bf, wv_bf, partials);
  dora_pass2<<<1, 256, 0, stream>>>(partials, mag_q, mag_v, scales);

  gemm_qk<<<dim3(32, 16), 256, 0, stream>>>(qA_bf, wq_bf, kw_bf,
                                            bias_q, k_b, scales, qbuf, kbuf);
  gemm_vT<<<dim3(8, 32), 256, 0, stream>>>(wv_bf, qA_bf, bias_v, scales, vTbuf);
  attn_mfma<<<dim3(T_DIM / 128, B_DIM * H_DIM), 256, 0, stream>>>(qbuf, kbuf, vTbuf, abuf);
  gemm_out<<<dim3(32, 8), 256, 0, stream>>>(abuf, ow_bf, out_b, out);
}

// Round 5
// 193.896 us; speedup vs baseline: 9.9873x; 1.5028x over previous
//
#include <hip/hip_runtime.h>
#include <hip/hip_bf16.h>

// Problem constants
#define E_DIM 1024
#define T_DIM 2048
#define B_DIM 2
#define H_DIM 16
#define HD_DIM 64
#define R_DIM 8
#define M_ROWS (T_DIM * B_DIM)   // 4096 rows for all projections
#define LOG2E 1.4426950408889634f

typedef __attribute__((ext_vector_type(8))) short bf16x8;   // 8 bf16 (4 VGPRs)
typedef __attribute__((ext_vector_type(4))) float f32x4;    // 4 fp32 acc

#if __has_builtin(__builtin_amdgcn_exp2f)
#define EXP2F(x) __builtin_amdgcn_exp2f(x)
#else
#define EXP2F(x) exp2f(x)
#endif

// round-to-nearest-even f32 -> bf16 (as raw ushort)
__device__ __forceinline__ unsigned short f2bf(float f) {
  unsigned int u = __builtin_bit_cast(unsigned int, f);
  u += 0x7FFFu + ((u >> 16) & 1u);
  return (unsigned short)(u >> 16);
}

// packed f32x2 -> bf16x2 (RNE), src0 -> low16
__device__ __forceinline__ unsigned cvt_pk_bf16(float lo, float hi) {
  unsigned r;
  asm("v_cvt_pk_bf16_f32 %0, %1, %2" : "=v"(r) : "v"(lo), "v"(hi));
  return r;
}

// async global -> LDS, 16B per lane (dest must be wave-uniform base + lane*16)
__device__ __forceinline__ void glds16(const unsigned short* g, unsigned short* l) {
  __builtin_amdgcn_global_load_lds(
      (__attribute__((address_space(1))) void*)(g),
      (__attribute__((address_space(3))) void*)(l), 16, 0, 0);
}

// ---------------------------------------------------------------------------
// prep: fused f32->bf16 converts (query, k_w, out_w) + DoRA pass1
// grid: 6656 blocks of 256. Blocks [0,6144): converts; [6144,6656): dora.
// ---------------------------------------------------------------------------
__global__ __launch_bounds__(256) void prep(
    const float* __restrict__ query, const float* __restrict__ k_w,
    const float* __restrict__ out_w,
    const float* __restrict__ dir_q, const float* __restrict__ A_q, const float* __restrict__ B_q,
    const float* __restrict__ dir_v, const float* __restrict__ A_v, const float* __restrict__ B_v,
    unsigned short* __restrict__ qA_bf, unsigned short* __restrict__ kw_bf,
    unsigned short* __restrict__ ow_bf,
    unsigned short* __restrict__ Wq, unsigned short* __restrict__ Wv,
    float* __restrict__ partials) {
  const int bid = blockIdx.x;
  if (bid < 6144) {
    int u = bid * 256 + threadIdx.x;     // float4 units, total exactly 1572864
    const float* src;
    unsigned short* dst;
    if (u < 1048576) { src = query; dst = qA_bf; }
    else if (u < 1310720) { src = k_w; dst = kw_bf; u -= 1048576; }
    else { src = out_w; dst = ow_bf; u -= 1310720; }
    float4 f = reinterpret_cast<const float4*>(src)[u];
    ushort4 o;
    o.x = f2bf(f.x); o.y = f2bf(f.y); o.z = f2bf(f.z); o.w = f2bf(f.w);
    reinterpret_cast<ushort4*>(dst)[u] = o;
    return;
  }
  // DoRA pass1: Vu = dir + B@A -> bf16 W, fp32 partial sums of Vu^2
  const int bid2 = bid - 6144;
  const int mat = bid2 >> 8, bx = bid2 & 255;
  const float* __restrict__ dir = mat ? dir_v : dir_q;
  const float* __restrict__ Am  = mat ? A_v   : A_q;
  const float* __restrict__ Bm  = mat ? B_v   : B_q;
  unsigned short* __restrict__ W = mat ? Wv : Wq;

  float sum = 0.0f;
  for (int idx = bx * 256 + threadIdx.x; idx < E_DIM * E_DIM; idx += 256 * 256) {
    int i = idx >> 10;
    int j = idx & (E_DIM - 1);
    float v = dir[idx];
#pragma unroll
    for (int r = 0; r < R_DIM; ++r)
      v += Bm[i * R_DIM + r] * Am[r * E_DIM + j];
    W[idx] = f2bf(v);
    sum += v * v;          // norm on fp32 values (matches reference)
  }
#pragma unroll
  for (int off = 32; off > 0; off >>= 1) sum += __shfl_down(sum, off);
  __shared__ float red[4];
  if ((threadIdx.x & 63) == 0) red[threadIdx.x >> 6] = sum;
  __syncthreads();
  if (threadIdx.x == 0)
    partials[mat * 256 + bx] = (red[0] + red[1]) + (red[2] + red[3]);
}

// ---------------------------------------------------------------------------
// Pass 2: scales[0]=m_q/(||Vu_q||+1e-8), scales[1]=m_v/(...)
// ---------------------------------------------------------------------------
__global__ __launch_bounds__(256) void dora_pass2(
    const float* __restrict__ partials, const float* __restrict__ mag_q,
    const float* __restrict__ mag_v, float* __restrict__ scales) {
  __shared__ float red[4];
  for (int mat = 0; mat < 2; ++mat) {
    float s = partials[mat * 256 + threadIdx.x];
#pragma unroll
    for (int off = 32; off > 0; off >>= 1) s += __shfl_down(s, off);
    if ((threadIdx.x & 63) == 0) red[threadIdx.x >> 6] = s;
    __syncthreads();
    if (threadIdx.x == 0) {
      float tot = (red[0] + red[1]) + (red[2] + red[3]);
      float m = mat ? mag_v[0] : mag_q[0];
      scales[mat] = m / (sqrtf(tot) + 1e-8f);
    }
    __syncthreads();
  }
}

// ---------------------------------------------------------------------------
// bf16 MFMA GEMM core: C = scale*(A @ W^T) + bscale*bias. 128x128 tile, BK=32,
// 256 thr (4 waves 2x2), 4x4 frags/wave. Staging via global_load_lds width-16
// (m97 structure, 2-barrier loop).
// OUT_MODE: 0 = f32 C[row][col]; 1 = bf16 C[row][col];
//           2 = bf16 V^T scatter vT[b][h][d][t], bias indexed by A-row.
// ---------------------------------------------------------------------------
template <int OUT_MODE>
__device__ __forceinline__ void gemm_bt_core(
    const unsigned short* __restrict__ A, const unsigned short* __restrict__ W,
    const float* __restrict__ bias, float scale, float bscale,
    void* __restrict__ Cptr, int bm, int bn) {
  __shared__ unsigned short As[128 * 32];
  __shared__ unsigned short Bs[128 * 32];
  const int tid = threadIdx.x;
  const int w = tid >> 6, lane = tid & 63;
  const int lr = lane & 15, lg = lane >> 4;
  const int wm = w >> 1, wn = w & 1;

  f32x4 acc[4][4];
#pragma unroll
  for (int i = 0; i < 4; ++i)
#pragma unroll
    for (int j = 0; j < 4; ++j) acc[i][j] = (f32x4){0.f, 0.f, 0.f, 0.f};

  // staging decomposition: unit c = it*256+tid -> row r=c>>2, col off=(c&3)*8
  const int c0u = tid, c1u = 256 + tid;
  const int r0 = c0u >> 2, o0 = (c0u & 3) * 8;
  const int r1 = c1u >> 2, o1 = (c1u & 3) * 8;

  for (int k0 = 0; k0 < E_DIM; k0 += 32) {
    glds16(A + (size_t)(bm + r0) * E_DIM + k0 + o0, As + c0u * 8);
    glds16(W + (size_t)(bn + r0) * E_DIM + k0 + o0, Bs + c0u * 8);
    glds16(A + (size_t)(bm + r1) * E_DIM + k0 + o1, As + c1u * 8);
    glds16(W + (size_t)(bn + r1) * E_DIM + k0 + o1, Bs + c1u * 8);
    __syncthreads();   // compiler drains vmcnt(0) before barrier

    bf16x8 af[4], bf[4];
#pragma unroll
    for (int i = 0; i < 4; ++i)
      af[i] = *reinterpret_cast<const bf16x8*>(As + (wm * 64 + i * 16 + lr) * 32 + lg * 8);
#pragma unroll
    for (int j = 0; j < 4; ++j)
      bf[j] = *reinterpret_cast<const bf16x8*>(Bs + (wn * 64 + j * 16 + lr) * 32 + lg * 8);
#pragma unroll
    for (int i = 0; i < 4; ++i)
#pragma unroll
      for (int j = 0; j < 4; ++j)
        acc[i][j] = __builtin_amdgcn_mfma_f32_16x16x32_bf16(af[i], bf[j], acc[i][j], 0, 0, 0);
    __syncthreads();   // all reads done before next stage overwrites
  }

  if (OUT_MODE == 2) {
    // C^T scatter: A-row = V out-dim (wrow), W-row = token row (xrow).
#pragma unroll
    for (int i = 0; i < 4; ++i) {
      int rowbase = bm + wm * 64 + i * 16 + lg * 4;
      float4 bb = *reinterpret_cast<const float4*>(&bias[rowbase]);
      float bbv[4] = {bb.x, bb.y, bb.z, bb.w};
#pragma unroll
      for (int j = 0; j < 4; ++j) {
        int xrow = bn + wn * 64 + j * 16 + lr;
        int t = xrow >> 1, bsel = xrow & 1;
#pragma unroll
        for (int rr = 0; rr < 4; ++rr) {
          int wrow = rowbase + rr;
          float v = scale * acc[i][j][rr] + bbv[rr];
          int nn = (bsel << 4) | (wrow >> 6);
          int d = wrow & 63;
          reinterpret_cast<unsigned short*>(Cptr)[((size_t)nn * HD_DIM + d) * T_DIM + t] = f2bf(v);
        }
      }
    }
  } else {
#pragma unroll
    for (int i = 0; i < 4; ++i) {
      int row = bm + wm * 64 + i * 16 + lg * 4;
#pragma unroll
      for (int j = 0; j < 4; ++j) {
        int col = bn + wn * 64 + j * 16 + lr;
        float bv = bias[col] * bscale;
#pragma unroll
        for (int r = 0; r < 4; ++r) {
          float v = scale * acc[i][j][r] + bv;
          if (OUT_MODE == 1)
            reinterpret_cast<unsigned short*>(Cptr)[(size_t)(row + r) * E_DIM + col] = f2bf(v);
          else
            reinterpret_cast<float*>(Cptr)[(size_t)(row + r) * E_DIM + col] = v;
        }
      }
    }
  }
}

// Fused Q + K + V^T projections: grid 768, XCD-swizzled (768 % 8 == 0).
// swz [0,256): Q; [256,512): K; [512,768): V^T.
__global__ __launch_bounds__(256) void gemm_qkv(
    const unsigned short* __restrict__ Abf,
    const unsigned short* __restrict__ Wq, const unsigned short* __restrict__ Wk,
    const unsigned short* __restrict__ Wv,
    const float* __restrict__ bias_q, const float* __restrict__ k_b,
    const float* __restrict__ bias_v, const float* __restrict__ scales,
    unsigned short* __restrict__ qbuf, unsigned short* __restrict__ kbuf,
    unsigned short* __restrict__ vT) {
  const int bid = blockIdx.x;
  const int swz = (bid & 7) * 96 + (bid >> 3);
  if (swz < 512) {
    const int mat = swz >> 8;          // 0=q, 1=k
    const int idx = swz & 255;
    const int bm = (idx >> 3) * 128, bn = (idx & 7) * 128;
    if (mat == 0) {
      // fold softmax scale * log2(e) into q projection (matmul AND bias)
      const float sm = 0.125f * LOG2E;
      gemm_bt_core<1>(Abf, Wq, bias_q, scales[0] * sm, sm, qbuf, bm, bn);
    } else {
      gemm_bt_core<1>(Abf, Wk, k_b, 1.0f, 1.0f, kbuf, bm, bn);
    }
  } else {
    const int idx = swz - 512;
    gemm_bt_core<2>(Wv, Abf, bias_v, scales[1], 1.0f, vT,
                    (idx >> 5) * 128, (idx & 31) * 128);
  }
}

// Output projection: bf16 in, f32 out; grid 256, XCD-swizzled
__global__ __launch_bounds__(256) void gemm_out(
    const unsigned short* __restrict__ Abf, const unsigned short* __restrict__ Wo,
    const float* __restrict__ bias, float* __restrict__ out) {
  const int bid = blockIdx.x;
  const int swz = (bid & 7) * 32 + (bid >> 3);
  gemm_bt_core<0>(Abf, Wo, bias, 1.0f, 1.0f, out, (swz >> 3) * 128, (swz & 7) * 128);
}

// ---------------------------------------------------------------------------
// Flash attention, bf16 MFMA, swapped QK^T, exp2-domain softmax (log2e folded
// into q), defer-max rescale (THR=8), cvt_pk P-packing, shfl-based alpha/l
// broadcast. 4 waves x 32 q-rows, KV-tile 64. grid: (T/128, B*H)
// ---------------------------------------------------------------------------
#define LDP 72

__global__ __launch_bounds__(256) void attn_mfma(
    const unsigned short* __restrict__ qb, const unsigned short* __restrict__ kb,
    const unsigned short* __restrict__ vT, unsigned short* __restrict__ ob) {
  __shared__ unsigned short Ks[64 * LDP];
  __shared__ unsigned short Vt[64 * LDP];
  __shared__ unsigned short Ps[4][32 * LDP];
  const int n = blockIdx.y, b = n >> 4, col0 = (n & 15) * HD_DIM;
  const int tid = threadIdx.x, w = tid >> 6, lane = tid & 63;
  const int lr = lane & 15, lg = lane >> 4;
  const int q0 = blockIdx.x * 128 + w * 32;
  unsigned short* Pw = Ps[w];

  // Q fragments, resident whole kernel
  bf16x8 qf[2][2];
#pragma unroll
  for (int rf = 0; rf < 2; ++rf)
#pragma unroll
    for (int ks = 0; ks < 2; ++ks)
      qf[rf][ks] = *reinterpret_cast<const bf16x8*>(
          qb + ((size_t)(q0 + rf * 16 + lr) * B_DIM + b) * E_DIM + col0 + ks * 32 + lg * 8);

  f32x4 accO[2][4];
#pragma unroll
  for (int rf = 0; rf < 2; ++rf)
#pragma unroll
    for (int df = 0; df < 4; ++df) accO[rf][df] = (f32x4){0.f, 0.f, 0.f, 0.f};
  float mrun0 = -1e30f, mrun1 = -1e30f, lrun0 = 0.f, lrun1 = 0.f;

  // staging decomposition (per thread, 2 float4 units each for K and V)
  const int sr0 = tid >> 3, sc0 = (tid & 7) * 8;
  const int sr1 = 32 + sr0;
  float4 rk[2], rv[2];
  rk[0] = *reinterpret_cast<const float4*>(kb + ((size_t)sr0 * B_DIM + b) * E_DIM + col0 + sc0);
  rk[1] = *reinterpret_cast<const float4*>(kb + ((size_t)sr1 * B_DIM + b) * E_DIM + col0 + sc0);
  rv[0] = *reinterpret_cast<const float4*>(vT + ((size_t)n * HD_DIM + sr0) * T_DIM + sc0);
  rv[1] = *reinterpret_cast<const float4*>(vT + ((size_t)n * HD_DIM + sr1) * T_DIM + sc0);

  for (int kt = 0; kt < T_DIM; kt += 64) {
    __syncthreads();   // all waves done reading previous tile
    *reinterpret_cast<float4*>(Ks + sr0 * LDP + sc0) = rk[0];
    *reinterpret_cast<float4*>(Ks + sr1 * LDP + sc0) = rk[1];
    *reinterpret_cast<float4*>(Vt + sr0 * LDP + sc0) = rv[0];
    *reinterpret_cast<float4*>(Vt + sr1 * LDP + sc0) = rv[1];
    __syncthreads();
    if (kt + 64 < T_DIM) {   // prefetch next tile into regs
      int kt2 = kt + 64;
      rk[0] = *reinterpret_cast<const float4*>(kb + ((size_t)(kt2 + sr0) * B_DIM + b) * E_DIM + col0 + sc0);
      rk[1] = *reinterpret_cast<const float4*>(kb + ((size_t)(kt2 + sr1) * B_DIM + b) * E_DIM + col0 + sc0);
      rv[0] = *reinterpret_cast<const float4*>(vT + ((size_t)n * HD_DIM + sr0) * T_DIM + kt2 + sc0);
      rv[1] = *reinterpret_cast<const float4*>(vT + ((size_t)n * HD_DIM + sr1) * T_DIM + kt2 + sc0);
    }

    // S^T = K Q^T: lane holds q = q0+rf*16+lr, k = kf*16+lg*4+r (log2e folded)
    f32x4 s[4][2];
#pragma unroll
    for (int kf = 0; kf < 4; ++kf)
#pragma unroll
      for (int rf = 0; rf < 2; ++rf) s[kf][rf] = (f32x4){0.f, 0.f, 0.f, 0.f};
#pragma unroll
    for (int ks = 0; ks < 2; ++ks)
#pragma unroll
      for (int kf = 0; kf < 4; ++kf) {
        bf16x8 kfr = *reinterpret_cast<const bf16x8*>(Ks + (kf * 16 + lr) * LDP + ks * 32 + lg * 8);
#pragma unroll
        for (int rf = 0; rf < 2; ++rf)
          s[kf][rf] = __builtin_amdgcn_mfma_f32_16x16x32_bf16(kfr, qf[rf][ks], s[kf][rf], 0, 0, 0);
      }

    // row max (tree, depth 4) + cross-lg reduce
    float pm0, pm1;
    {
      float a0 = fmaxf(fmaxf(s[0][0][0], s[0][0][1]), fmaxf(s[0][0][2], s[0][0][3]));
      float a1 = fmaxf(fmaxf(s[1][0][0], s[1][0][1]), fmaxf(s[1][0][2], s[1][0][3]));
      float a2 = fmaxf(fmaxf(s[2][0][0], s[2][0][1]), fmaxf(s[2][0][2], s[2][0][3]));
      float a3 = fmaxf(fmaxf(s[3][0][0], s[3][0][1]), fmaxf(s[3][0][2], s[3][0][3]));
      pm0 = fmaxf(fmaxf(a0, a1), fmaxf(a2, a3));
      float b0 = fmaxf(fmaxf(s[0][1][0], s[0][1][1]), fmaxf(s[0][1][2], s[0][1][3]));
      float b1 = fmaxf(fmaxf(s[1][1][0], s[1][1][1]), fmaxf(s[1][1][2], s[1][1][3]));
      float b2 = fmaxf(fmaxf(s[2][1][0], s[2][1][1]), fmaxf(s[2][1][2], s[2][1][3]));
      float b3 = fmaxf(fmaxf(s[3][1][0], s[3][1][1]), fmaxf(s[3][1][2], s[3][1][3]));
      pm1 = fmaxf(fmaxf(b0, b1), fmaxf(b2, b3));
    }
    pm0 = fmaxf(pm0, __shfl_xor(pm0, 16)); pm0 = fmaxf(pm0, __shfl_xor(pm0, 32));
    pm1 = fmaxf(pm1, __shfl_xor(pm1, 16)); pm1 = fmaxf(pm1, __shfl_xor(pm1, 32));

    // defer-max: skip rescale unless some row's max grew past THR=8 (exp2 dom)
    const int resc = __any((pm0 > mrun0 + 8.0f) || (pm1 > mrun1 + 8.0f));
    float mn0 = mrun0, mn1 = mrun1;
    if (resc) { mn0 = fmaxf(mn0, pm0); mn1 = fmaxf(mn1, pm1); }

    // p = exp2(s - mn) in place
#pragma unroll
    for (int kf = 0; kf < 4; ++kf)
#pragma unroll
      for (int r = 0; r < 4; ++r) {
        s[kf][0][r] = EXP2F(s[kf][0][r] - mn0);
        s[kf][1][r] = EXP2F(s[kf][1][r] - mn1);
      }

    // P -> Pw packed via v_cvt_pk_bf16_f32 (writes early; reads after psum)
#pragma unroll
    for (int rf = 0; rf < 2; ++rf)
#pragma unroll
      for (int kf = 0; kf < 4; ++kf) {
        uint2 pk;
        pk.x = cvt_pk_bf16(s[kf][rf][0], s[kf][rf][1]);
        pk.y = cvt_pk_bf16(s[kf][rf][2], s[kf][rf][3]);
        *reinterpret_cast<uint2*>(Pw + (rf * 16 + lr) * LDP + kf * 16 + lg * 4) = pk;
      }

    // psum (vector tree) + cross-lg reduce
    f32x4 u0 = (s[0][0] + s[1][0]) + (s[2][0] + s[3][0]);
    f32x4 u1 = (s[0][1] + s[1][1]) + (s[2][1] + s[3][1]);
    float ps0 = (u0[0] + u0[1]) + (u0[2] + u0[3]);
    float ps1 = (u1[0] + u1[1]) + (u1[2] + u1[3]);
    ps0 += __shfl_xor(ps0, 16); ps0 += __shfl_xor(ps0, 32);
    ps1 += __shfl_xor(ps1, 16); ps1 += __shfl_xor(ps1, 32);

    if (resc) {
      float al0 = EXP2F(mrun0 - mn0), al1 = EXP2F(mrun1 - mn1);
      mrun0 = mn0; mrun1 = mn1;
      lrun0 = lrun0 * al0 + ps0; lrun1 = lrun1 * al1 + ps1;
#pragma unroll
      for (int r = 0; r < 4; ++r) {
        float a0 = __shfl(al0, (lg << 2) | r);
        float a1 = __shfl(al1, (lg << 2) | r);
#pragma unroll
        for (int df = 0; df < 4; ++df) { accO[0][df][r] *= a0; accO[1][df][r] *= a1; }
      }
    } else {
      lrun0 += ps0; lrun1 += ps1;
    }

    // O += P V (per-wave Pw: same-wave LDS ordering via lgkmcnt)
#pragma unroll
    for (int ks = 0; ks < 2; ++ks) {
      bf16x8 pa0 = *reinterpret_cast<const bf16x8*>(Pw + lr * LDP + ks * 32 + lg * 8);
      bf16x8 pa1 = *reinterpret_cast<const bf16x8*>(Pw + (16 + lr) * LDP + ks * 32 + lg * 8);
#pragma unroll
      for (int df = 0; df < 4; ++df) {
        bf16x8 vf = *reinterpret_cast<const bf16x8*>(Vt + (df * 16 + lr) * LDP + ks * 32 + lg * 8);
        accO[0][df] = __builtin_amdgcn_mfma_f32_16x16x32_bf16(pa0, vf, accO[0][df], 0, 0, 0);
        accO[1][df] = __builtin_amdgcn_mfma_f32_16x16x32_bf16(pa1, vf, accO[1][df], 0, 0, 0);
      }
    }
  }

  // normalize (l broadcast via shfl) + write bf16
#pragma unroll
  for (int rf = 0; rf < 2; ++rf)
#pragma unroll
    for (int r = 0; r < 4; ++r) {
      float lv = __shfl(rf ? lrun1 : lrun0, (lg << 2) | r);
      float inv = 1.0f / lv;
      int row = q0 + rf * 16 + lg * 4 + r;
      size_t base = ((size_t)row * B_DIM + b) * E_DIM + col0;
#pragma unroll
      for (int df = 0; df < 4; ++df)
        ob[base + df * 16 + lr] = f2bf(accO[rf][df][r] * inv);
    }
}

// ---------------------------------------------------------------------------
extern "C" void kernel_launch(void* const* d_in, const int* in_sizes, int n_in,
                              void* d_out, int out_size, void* d_ws, size_t ws_size,
                              hipStream_t stream) {
  const float* query  = (const float*)d_in[0];
  const float* mag_q  = (const float*)d_in[3];
  const float* dir_q  = (const float*)d_in[4];
  const float* A_q    = (const float*)d_in[5];
  const float* B_q    = (const float*)d_in[6];
  const float* bias_q = (const float*)d_in[7];
  const float* mag_v  = (const float*)d_in[8];
  const float* dir_v  = (const float*)d_in[9];
  const float* A_v    = (const float*)d_in[10];
  const float* B_v    = (const float*)d_in[11];
  const float* bias_v = (const float*)d_in[12];
  const float* k_w    = (const float*)d_in[13];
  const float* k_b    = (const float*)d_in[14];
  const float* out_w  = (const float*)d_in[15];
  const float* out_b  = (const float*)d_in[16];
  float* out = (float*)d_out;

  // workspace layout (~48 MB, all regions fully rewritten every call)
  char* ws = (char*)d_ws;
  float* partials = (float*)ws;                          // 2048 B
  float* scales   = (float*)(ws + 2048);                 // 2 f32
  unsigned short* qA_bf = (unsigned short*)(ws + 4096);  // query bf16, 8 MB
  unsigned short* wq_bf = qA_bf + (size_t)M_ROWS * E_DIM;
  unsigned short* wv_bf = wq_bf + (size_t)E_DIM * E_DIM;
  unsigned short* kw_bf = wv_bf + (size_t)E_DIM * E_DIM;
  unsigned short* ow_bf = kw_bf + (size_t)E_DIM * E_DIM;
  unsigned short* qbuf  = ow_bf + (size_t)E_DIM * E_DIM;
  unsigned short* kbuf  = qbuf + (size_t)M_ROWS * E_DIM;
  unsigned short* vTbuf = kbuf + (size_t)M_ROWS * E_DIM;  // [b][h][d][t]
  unsigned short* abuf  = vTbuf + (size_t)M_ROWS * E_DIM;

  prep<<<6656, 256, 0, stream>>>(query, k_w, out_w,
                                 dir_q, A_q, B_q, dir_v, A_v, B_v,
                                 qA_bf, kw_bf, ow_bf, wq_bf, wv_bf, partials);
  dora_pass2<<<1, 256, 0, stream>>>(partials, mag_q, mag_v, scales);

  gemm_qkv<<<768, 256, 0, stream>>>(qA_bf, wq_bf, kw_bf, wv_bf,
                                    bias_q, k_b, bias_v, scales,
                                    qbuf, kbuf, vTbuf);
  attn_mfma<<<dim3(T_DIM / 128, B_DIM * H_DIM), 256, 0, stream>>>(qbuf, kbuf, vTbuf, abuf);
  gemm_out<<<256, 256, 0, stream>>>(abuf, ow_bf, out_b, out);
}